// Round 4
// baseline (968.402 us; speedup 1.0000x reference)
//
#include <hip/hip_runtime.h>
#include <hip/hip_bf16.h>
#include <stdint.h>

#define B_   128
#define LT   256
#define LI   576
#define HD   1024
#define SMOOTHF 9.0f
#define EPSF 1e-8f

typedef __bf16 bf16x8 __attribute__((ext_vector_type(8)));
typedef float  f32x4  __attribute__((ext_vector_type(4)));

__device__ inline ushort f2b(float f) {
  uint32_t u = __float_as_uint(f);
  u += 0x7FFFu + ((u >> 16) & 1u);   // RNE
  return (ushort)(u >> 16);
}

// async global->LDS, 16B per lane. LDS dest is wave-uniform base + lane*16.
__device__ __forceinline__ void gload_lds16(const ushort* g, ushort* l) {
  __builtin_amdgcn_global_load_lds(
      (const __attribute__((address_space(1))) unsigned int*)(g),
      (__attribute__((address_space(3))) unsigned int*)(l),
      16, 0, 0);
}

// ---------------- fp32 -> bf16 (plain, for weights) ----------------
__global__ __launch_bounds__(256) void cvt_bf16_kernel(
    const float* __restrict__ in, ushort* __restrict__ out, int n4) {
  int idx = blockIdx.x * blockDim.x + threadIdx.x;
  int stride = gridDim.x * blockDim.x;
  for (int i = idx; i < n4; i += stride) {
    float4 v = reinterpret_cast<const float4*>(in)[i];
    ushort4 o = make_ushort4(f2b(v.x), f2b(v.y), f2b(v.z), f2b(v.w));
    reinterpret_cast<ushort4*>(out)[i] = o;
  }
}

// ---------------- fp32 -> bf16 normal + transposed copies ----------------
// in: [B][R][HD] fp32.  outN: [B][R][HD] bf16.  outT: [B][HD][R] bf16.
// 64x64 tiles via LDS float T[64][65] (2-way-max bank aliasing = free).
__global__ __launch_bounds__(256) void cvtT_kernel(
    const float* __restrict__ in, ushort* __restrict__ outN,
    ushort* __restrict__ outT, int R) {
  __shared__ float T[64][65];
  int b = blockIdx.y;
  int nrt = R >> 6;
  int rt = blockIdx.x % nrt, ct = blockIdx.x / nrt;
  int r0 = rt << 6, c0 = ct << 6;
  const float* src = in + ((size_t)b * R + r0) * HD + c0;
  ushort* dN = outN + ((size_t)b * R + r0) * HD + c0;
  ushort* dT = outT + ((size_t)b * HD + c0) * R + r0;
  int tid = threadIdx.x;
  #pragma unroll
  for (int j = 0; j < 4; ++j) {
    int q = tid + j * 256;
    int row = q >> 4;              // 0..63 (r within tile)
    int c4  = (q & 15) << 2;       // 0..60 (c within tile)
    float4 v = *reinterpret_cast<const float4*>(src + (size_t)row * HD + c4);
    reinterpret_cast<ushort4*>(dN + (size_t)row * HD)[c4 >> 2] =
        make_ushort4(f2b(v.x), f2b(v.y), f2b(v.z), f2b(v.w));
    T[c4 + 0][row] = v.x;
    T[c4 + 1][row] = v.y;
    T[c4 + 2][row] = v.z;
    T[c4 + 3][row] = v.w;
  }
  __syncthreads();
  #pragma unroll
  for (int j = 0; j < 4; ++j) {
    int q = tid + j * 256;
    int crow = q >> 4;             // c within tile (output row)
    int r4   = (q & 15) << 2;      // r within tile
    ushort4 o = make_ushort4(f2b(T[crow][r4]), f2b(T[crow][r4 + 1]),
                             f2b(T[crow][r4 + 2]), f2b(T[crow][r4 + 3]));
    reinterpret_cast<ushort4*>(dT + (size_t)crow * R)[r4 >> 2] = o;
  }
}

// ---------------- m97-structure GEMM: 128x128 tile, BK=64, 4 waves, NT only ----
// C[m,n] = sum_k A[m,k]*B[n,k].  Both operands K-contiguous, global_load_lds.
template<bool MPRED, bool OUT_BF16, bool RELU_BIAS, bool SWZ>
__global__ __launch_bounds__(256)
void gemm128(const ushort* __restrict__ A, const ushort* __restrict__ Bm,
             const float* __restrict__ bias, void* __restrict__ C,
             int M, int N, int K,
             long sA, long sB, long sC, int lda, int ldb, int ldc)
{
  __shared__ ushort As[128][64];
  __shared__ ushort Bs[128][64];
  const int b = blockIdx.y;
  int bid = blockIdx.x;
  if (SWZ) {                                  // XCD swizzle (nwg % 8 == 0)
    int cpx = gridDim.x >> 3;
    bid = (bid & 7) * cpx + (bid >> 3);
  }
  const int ntiles = N >> 7;
  const int m0 = (bid / ntiles) << 7;
  const int n0 = (bid % ntiles) << 7;
  const ushort* Ab = A + (size_t)b * sA;
  const ushort* Bb = Bm + (size_t)b * sB;

  const int t    = threadIdx.x;
  const int lane = t & 63, w = t >> 6;
  const int wr = w >> 1, wc = w & 1;          // 2x2 waves, 64x64 out each
  const int r16 = lane & 15, g = lane >> 4;

  const int srow = lane >> 3;                 // 0..7
  const int scol = (lane & 7) << 3;           // 0..56

  f32x4 acc[4][4] = {};

  for (int k0 = 0; k0 < K; k0 += 64) {
    #pragma unroll
    for (int j = 0; j < 4; ++j) {
      int row = j * 32 + w * 8 + srow;
      int ar = m0 + row;
      if (MPRED) ar = ar < M ? ar : M - 1;
      gload_lds16(Ab + (size_t)ar * lda + k0 + scol, &As[0][0] + j * 2048 + w * 512);
    }
    #pragma unroll
    for (int j = 0; j < 4; ++j) {
      int row = j * 32 + w * 8 + srow;
      gload_lds16(Bb + (size_t)(n0 + row) * ldb + k0 + scol, &Bs[0][0] + j * 2048 + w * 512);
    }
    __syncthreads();
    #pragma unroll
    for (int kk = 0; kk < 2; ++kk) {
      bf16x8 af[4], bf[4];
      #pragma unroll
      for (int f = 0; f < 4; ++f) {
        af[f] = *reinterpret_cast<const bf16x8*>(&As[wr * 64 + f * 16 + r16][kk * 32 + g * 8]);
        bf[f] = *reinterpret_cast<const bf16x8*>(&Bs[wc * 64 + f * 16 + r16][kk * 32 + g * 8]);
      }
      #pragma unroll
      for (int fr = 0; fr < 4; ++fr)
        #pragma unroll
        for (int fc = 0; fc < 4; ++fc)
          acc[fr][fc] = __builtin_amdgcn_mfma_f32_16x16x32_bf16(af[fr], bf[fc], acc[fr][fc], 0, 0, 0);
    }
    __syncthreads();
  }

  // epilogue: C/D layout col=lane&15, row=(lane>>4)*4+reg [m89-verified]
  #pragma unroll
  for (int fr = 0; fr < 4; ++fr) {
    int rbase = m0 + wr * 64 + fr * 16 + g * 4;
    #pragma unroll
    for (int r = 0; r < 4; ++r) {
      if (MPRED && (rbase + r >= M)) continue;
      size_t off0 = (size_t)b * sC + (size_t)(rbase + r) * ldc + n0 + wc * 64;
      #pragma unroll
      for (int fc = 0; fc < 4; ++fc) {
        int col = fc * 16 + r16;
        float v = acc[fr][fc][r];
        if (RELU_BIAS) v = fmaxf(v + bias[n0 + wc * 64 + col], 0.0f);
        if (OUT_BF16) reinterpret_cast<ushort*>(C)[off0 + col] = f2b(v);
        else          reinterpret_cast<float*>(C)[off0 + col]  = v;
      }
    }
  }
}

// ---------------- fused relu row+col sums over G (single pass) ----------------
// block = b*4 + ch, ch covers 144 rows. rs_t[b,i] full; csp[blk][t] col partials.
__global__ __launch_bounds__(256) void gsums_kernel(
    const float* __restrict__ G, float* __restrict__ rs_t, float* __restrict__ csp) {
  __shared__ float cs[4][LT];
  int blk = blockIdx.x;
  int b = blk >> 2, ch = blk & 3;
  int w = threadIdx.x >> 6, lane = threadIdx.x & 63;
  const float* g = G + (size_t)b * LI * LT;
  int i0 = ch * 144;
  float c0 = 0.f, c1 = 0.f, c2 = 0.f, c3 = 0.f;
  for (int k = 0; k < 36; ++k) {
    int i = i0 + k * 4 + w;
    float4 v = reinterpret_cast<const float4*>(g + (size_t)i * LT)[lane];
    float r0 = fmaxf(v.x, 0.f), r1 = fmaxf(v.y, 0.f);
    float r2 = fmaxf(v.z, 0.f), r3 = fmaxf(v.w, 0.f);
    c0 += r0; c1 += r1; c2 += r2; c3 += r3;
    float s = r0 + r1 + r2 + r3;
    #pragma unroll
    for (int off = 32; off > 0; off >>= 1) s += __shfl_xor(s, off);
    if (lane == 0) rs_t[b * LI + i] = s;
  }
  cs[w][lane * 4 + 0] = c0;
  cs[w][lane * 4 + 1] = c1;
  cs[w][lane * 4 + 2] = c2;
  cs[w][lane * 4 + 3] = c3;
  __syncthreads();
  int t = threadIdx.x;
  csp[(size_t)blk * LT + t] = cs[0][t] + cs[1][t] + cs[2][t] + cs[3][t];
}

// ---------------- attn_txt[b,i,t] = softmax_t( 9*relu(G)/rs_i ) ----------------
__global__ __launch_bounds__(256) void attn_txt_kernel(
    const float* __restrict__ G, const float* __restrict__ csp,
    float* __restrict__ out_f32, ushort* __restrict__ out_bf16) {
  int row  = blockIdx.x * 4 + (threadIdx.x >> 6);
  int b    = row / LI;
  int lane = threadIdx.x & 63;
  float4 gv = reinterpret_cast<const float4*>(G + (size_t)row * LT)[lane];
  float4 dv = reinterpret_cast<const float4*>(csp + (size_t)(b * 4 + 0) * LT)[lane];
  #pragma unroll
  for (int ch = 1; ch < 4; ++ch) {
    float4 p = reinterpret_cast<const float4*>(csp + (size_t)(b * 4 + ch) * LT)[lane];
    dv.x += p.x; dv.y += p.y; dv.z += p.z; dv.w += p.w;
  }
  float x0 = SMOOTHF * fmaxf(gv.x, 0.f) / (dv.x + EPSF);
  float x1 = SMOOTHF * fmaxf(gv.y, 0.f) / (dv.y + EPSF);
  float x2 = SMOOTHF * fmaxf(gv.z, 0.f) / (dv.z + EPSF);
  float x3 = SMOOTHF * fmaxf(gv.w, 0.f) / (dv.w + EPSF);
  float m = fmaxf(fmaxf(x0, x1), fmaxf(x2, x3));
  #pragma unroll
  for (int off = 32; off > 0; off >>= 1) m = fmaxf(m, __shfl_xor(m, off));
  float e0 = __expf(x0 - m), e1 = __expf(x1 - m), e2 = __expf(x2 - m), e3 = __expf(x3 - m);
  float s = e0 + e1 + e2 + e3;
  #pragma unroll
  for (int off = 32; off > 0; off >>= 1) s += __shfl_xor(s, off);
  float inv = 1.0f / s;
  float4 o = make_float4(e0 * inv, e1 * inv, e2 * inv, e3 * inv);
  reinterpret_cast<float4*>(out_f32 + (size_t)row * LT)[lane] = o;
  ushort4 ob = make_ushort4(f2b(o.x), f2b(o.y), f2b(o.z), f2b(o.w));
  reinterpret_cast<ushort4*>(out_bf16 + (size_t)row * LT)[lane] = ob;
}

// ---------------- attn_img softmax stats over i (4 i-chunks) ----------------
__global__ __launch_bounds__(256) void attn_img_stats_kernel(
    const float* __restrict__ G, const float* __restrict__ rs_t,
    float* __restrict__ pm, float* __restrict__ ps) {
  __shared__ float inv_l[LI / 4];
  int b = blockIdx.x, iq = blockIdx.y, t = threadIdx.x;
  int i0 = iq * (LI / 4);
  for (int i = t; i < LI / 4; i += 256)
    inv_l[i] = SMOOTHF / (rs_t[b * LI + i0 + i] + EPSF);
  __syncthreads();
  const float* g = G + (size_t)b * LI * LT + (size_t)i0 * LT + t;
  float m = -1e30f, s = 0.f;
  for (int i = 0; i < LI / 4; ++i) {
    float x  = fmaxf(g[(size_t)i * LT], 0.f) * inv_l[i];
    float mn = fmaxf(m, x);
    s = s * __expf(m - mn) + __expf(x - mn);
    m = mn;
  }
  pm[(b * 4 + iq) * LT + t] = m;
  ps[(b * 4 + iq) * LT + t] = s;
}

__global__ __launch_bounds__(256) void attn_img_combine_kernel(
    const float* __restrict__ pm, const float* __restrict__ ps,
    float* __restrict__ m_out, float* __restrict__ s_out) {
  int b = blockIdx.x, t = threadIdx.x;
  float m = -1e30f;
  #pragma unroll
  for (int q = 0; q < 4; ++q) m = fmaxf(m, pm[(b * 4 + q) * LT + t]);
  float s = 0.f;
  #pragma unroll
  for (int q = 0; q < 4; ++q) s += ps[(b * 4 + q) * LT + t] * __expf(pm[(b * 4 + q) * LT + t] - m);
  m_out[b * LT + t] = m;
  s_out[b * LT + t] = s;
}

// ---------------- attn_img writer (G[i,t] -> attn[t,i] via LDS transpose) ------
__global__ __launch_bounds__(256) void attn_img_write_kernel(
    const float* __restrict__ G, const float* __restrict__ rs_t,
    const float* __restrict__ m_in, const float* __restrict__ s_in,
    float* __restrict__ out_f32, ushort* __restrict__ out_bf16) {
  __shared__ float T[64][65];
  int b  = blockIdx.y;
  int ti = blockIdx.x % (LI / 64);
  int tt = blockIdx.x / (LI / 64);
  int i0 = ti * 64, t0 = tt * 64;
  int tid = threadIdx.x;
  #pragma unroll
  for (int j = 0; j < 4; ++j) {
    int q = tid + j * 256;
    int row = q >> 4;
    int c4  = (q & 15) << 2;
    float4 gv = *reinterpret_cast<const float4*>(G + (size_t)b * LI * LT + (size_t)(i0 + row) * LT + t0 + c4);
    float inv = SMOOTHF / (rs_t[b * LI + i0 + row] + EPSF);
    float4 mt = *reinterpret_cast<const float4*>(m_in + b * LT + t0 + c4);
    float4 st = *reinterpret_cast<const float4*>(s_in + b * LT + t0 + c4);
    T[c4 + 0][row] = __expf(fmaxf(gv.x, 0.f) * inv - mt.x) / st.x;
    T[c4 + 1][row] = __expf(fmaxf(gv.y, 0.f) * inv - mt.y) / st.y;
    T[c4 + 2][row] = __expf(fmaxf(gv.z, 0.f) * inv - mt.z) / st.z;
    T[c4 + 3][row] = __expf(fmaxf(gv.w, 0.f) * inv - mt.w) / st.w;
  }
  __syncthreads();
  #pragma unroll
  for (int j = 0; j < 4; ++j) {
    int q = tid + j * 256;
    int row = q >> 4;
    int c4  = (q & 15) << 2;
    float4 o = make_float4(T[row][c4], T[row][c4 + 1], T[row][c4 + 2], T[row][c4 + 3]);
    size_t off = (size_t)b * LT * LI + (size_t)(t0 + row) * LI + i0 + c4;
    *reinterpret_cast<float4*>(out_f32 + off) = o;
    ushort4 ob = make_ushort4(f2b(o.x), f2b(o.y), f2b(o.z), f2b(o.w));
    *reinterpret_cast<ushort4*>(out_bf16 + off) = ob;
  }
}

// ---------------- launch ----------------
extern "C" void kernel_launch(void* const* d_in, const int* in_sizes, int n_in,
                              void* d_out, int out_size, void* d_ws, size_t ws_size,
                              hipStream_t stream) {
  const float* txt   = (const float*)d_in[0];
  const float* img   = (const float*)d_in[1];
  const float* W_txt = (const float*)d_in[2];
  const float* b_txt = (const float*)d_in[3];
  const float* W_img = (const float*)d_in[4];
  const float* b_img = (const float*)d_in[5];

  float* out          = (float*)d_out;
  float* out_txt      = out;
  float* out_img      = out + (size_t)B_ * LT * HD;
  float* out_attn_img = out_img + (size_t)B_ * LI * HD;
  float* out_attn_txt = out_attn_img + (size_t)B_ * LT * LI;

  char* w = (char*)d_ws;
  auto alloc = [&](size_t bytes) -> char* {
    char* p = w; w += (bytes + 255) & ~(size_t)255; return p;
  };
  ushort* txt_b  = (ushort*)alloc((size_t)B_ * LT * HD * 2);
  ushort* txtT_b = (ushort*)alloc((size_t)B_ * HD * LT * 2);
  ushort* img_b  = (ushort*)alloc((size_t)B_ * LI * HD * 2);
  ushort* imgT_b = (ushort*)alloc((size_t)B_ * HD * LI * 2);
  ushort* Wt_b   = (ushort*)alloc((size_t)HD * HD * 2);
  ushort* Wi_b   = (ushort*)alloc((size_t)HD * HD * 2);
  float*  Gm     = (float*) alloc((size_t)B_ * LI * LT * 4);
  float*  rs_t   = (float*) alloc((size_t)B_ * LI * 4);
  float*  csp    = (float*) alloc((size_t)B_ * 4 * LT * 4);
  float*  pm     = (float*) alloc((size_t)B_ * 4 * LT * 4);
  float*  ps     = (float*) alloc((size_t)B_ * 4 * LT * 4);
  float*  mi     = (float*) alloc((size_t)B_ * LT * 4);
  float*  si     = (float*) alloc((size_t)B_ * LT * 4);
  ushort* ai_b   = (ushort*)alloc((size_t)B_ * LT * LI * 2);
  ushort* at_b   = (ushort*)alloc((size_t)B_ * LI * LT * 2);
  ushort* txtAE  = (ushort*)alloc((size_t)B_ * LT * HD * 2);
  ushort* imgAE  = (ushort*)alloc((size_t)B_ * LI * HD * 2);
  (void)ws_size; (void)in_sizes; (void)n_in; (void)out_size;  // ~790 MB (ws ~2.2 GB per fill counters)

  // bf16 conversions (+ transposed context copies for NT AV GEMMs)
  cvtT_kernel<<<dim3((LT / 64) * (HD / 64), B_), 256, 0, stream>>>(txt, txt_b, txtT_b, LT);
  cvtT_kernel<<<dim3((LI / 64) * (HD / 64), B_), 256, 0, stream>>>(img, img_b, imgT_b, LI);
  cvt_bf16_kernel<<<1024, 256, 0, stream>>>(W_txt, Wt_b, HD * HD / 4);
  cvt_bf16_kernel<<<1024, 256, 0, stream>>>(W_img, Wi_b, HD * HD / 4);

  // G[b,i,t] = img[b,i,:].txt[b,t,:]   (NT, M=576 pred)
  dim3 gG(5 * (LT / 128), B_);
  gemm128<true, false, false, false><<<gG, 256, 0, stream>>>(
      img_b, txt_b, nullptr, Gm, LI, LT, HD,
      (long)LI * HD, (long)LT * HD, (long)LI * LT, HD, HD, LT);

  // fused relu row+col sums (single G pass)
  gsums_kernel<<<B_ * 4, 256, 0, stream>>>(Gm, rs_t, csp);

  attn_txt_kernel<<<B_ * LI / 4, 256, 0, stream>>>(Gm, csp, out_attn_txt, at_b);

  attn_img_stats_kernel<<<dim3(B_, 4), 256, 0, stream>>>(Gm, rs_t, pm, ps);
  attn_img_combine_kernel<<<B_, 256, 0, stream>>>(pm, ps, mi, si);
  attn_img_write_kernel<<<dim3((LT / 64) * (LI / 64), B_), 256, 0, stream>>>(
      Gm, rs_t, mi, si, out_attn_img, ai_b);

  // txtAE = attn_img . img   (NT via imgT_b [HD][LI])
  dim3 g1((LT / 128) * (HD / 128), B_);
  gemm128<false, true, false, false><<<g1, 256, 0, stream>>>(
      ai_b, imgT_b, nullptr, txtAE, LT, HD, LI,
      (long)LT * LI, (long)HD * LI, (long)LT * HD, LI, LI, HD);

  // imgAE = attn_txt . txt   (NT via txtT_b [HD][LT], M=576 pred)
  dim3 g2(5 * (HD / 128), B_);
  gemm128<true, true, false, false><<<g2, 256, 0, stream>>>(
      at_b, txtT_b, nullptr, imgAE, LI, HD, LT,
      (long)LI * LT, (long)HD * LT, (long)LI * HD, LT, LT, HD);

  // FC heads flattened over batch (shared W): relu(x @ W^T + b), NT, XCD swizzle
  dim3 gf1((B_ * LT / 128) * (HD / 128), 1);   // 2048 blocks
  gemm128<false, false, true, true><<<gf1, 256, 0, stream>>>(
      txtAE, Wt_b, b_txt, out_txt, B_ * LT, HD, HD,
      0L, 0L, 0L, HD, HD, HD);
  dim3 gf2((B_ * LI / 128) * (HD / 128), 1);   // 4608 blocks
  gemm128<false, false, true, true><<<gf2, 256, 0, stream>>>(
      imgAE, Wi_b, b_img, out_img, B_ * LI, HD, HD,
      0L, 0L, 0L, HD, HD, HD);
}

// Round 5
// 943.276 us; speedup vs baseline: 1.0266x; 1.0266x over previous
//
#include <hip/hip_runtime.h>
#include <hip/hip_bf16.h>
#include <stdint.h>

#define B_   128
#define LT   256
#define LI   576
#define HD   1024
#define SMOOTHF 9.0f
#define EPSF 1e-8f

typedef __bf16 bf16x8 __attribute__((ext_vector_type(8)));
typedef float  f32x4  __attribute__((ext_vector_type(4)));

__device__ inline ushort f2b(float f) {
  uint32_t u = __float_as_uint(f);
  u += 0x7FFFu + ((u >> 16) & 1u);   // RNE
  return (ushort)(u >> 16);
}
__device__ inline float b2f(ushort u) {
  return __uint_as_float((uint32_t)u << 16);
}

// async global->LDS, 16B per lane. LDS dest is wave-uniform base + lane*16.
__device__ __forceinline__ void gload_lds16(const ushort* g, ushort* l) {
  __builtin_amdgcn_global_load_lds(
      (const __attribute__((address_space(1))) unsigned int*)(g),
      (__attribute__((address_space(3))) unsigned int*)(l),
      16, 0, 0);
}

// ---------------- fp32 -> bf16 (plain, for weights) ----------------
__global__ __launch_bounds__(256) void cvt_bf16_kernel(
    const float* __restrict__ in, ushort* __restrict__ out, int n4) {
  int idx = blockIdx.x * blockDim.x + threadIdx.x;
  int stride = gridDim.x * blockDim.x;
  for (int i = idx; i < n4; i += stride) {
    float4 v = reinterpret_cast<const float4*>(in)[i];
    ushort4 o = make_ushort4(f2b(v.x), f2b(v.y), f2b(v.z), f2b(v.w));
    reinterpret_cast<ushort4*>(out)[i] = o;
  }
}

// ---------------- fp32 -> bf16 normal + transposed copies ----------------
__global__ __launch_bounds__(256) void cvtT_kernel(
    const float* __restrict__ in, ushort* __restrict__ outN,
    ushort* __restrict__ outT, int R) {
  __shared__ float T[64][65];
  int b = blockIdx.y;
  int nrt = R >> 6;
  int rt = blockIdx.x % nrt, ct = blockIdx.x / nrt;
  int r0 = rt << 6, c0 = ct << 6;
  const float* src = in + ((size_t)b * R + r0) * HD + c0;
  ushort* dN = outN + ((size_t)b * R + r0) * HD + c0;
  ushort* dT = outT + ((size_t)b * HD + c0) * R + r0;
  int tid = threadIdx.x;
  #pragma unroll
  for (int j = 0; j < 4; ++j) {
    int q = tid + j * 256;
    int row = q >> 4;
    int c4  = (q & 15) << 2;
    float4 v = *reinterpret_cast<const float4*>(src + (size_t)row * HD + c4);
    reinterpret_cast<ushort4*>(dN + (size_t)row * HD)[c4 >> 2] =
        make_ushort4(f2b(v.x), f2b(v.y), f2b(v.z), f2b(v.w));
    T[c4 + 0][row] = v.x;
    T[c4 + 1][row] = v.y;
    T[c4 + 2][row] = v.z;
    T[c4 + 3][row] = v.w;
  }
  __syncthreads();
  #pragma unroll
  for (int j = 0; j < 4; ++j) {
    int q = tid + j * 256;
    int crow = q >> 4;
    int r4   = (q & 15) << 2;
    ushort4 o = make_ushort4(f2b(T[crow][r4]), f2b(T[crow][r4 + 1]),
                             f2b(T[crow][r4 + 2]), f2b(T[crow][r4 + 3]));
    reinterpret_cast<ushort4*>(dT + (size_t)crow * R)[r4 >> 2] = o;
  }
}

// ---------------- m97-structure GEMM: 128x128 tile, BK=64, 4 waves, NT ----
template<bool MPRED, bool OUT_BF16, bool RELU_BIAS, bool SWZ>
__global__ __launch_bounds__(256)
void gemm128(const ushort* __restrict__ A, const ushort* __restrict__ Bm,
             const float* __restrict__ bias, void* __restrict__ C,
             int M, int N, int K,
             long sA, long sB, long sC, int lda, int ldb, int ldc)
{
  __shared__ ushort As[128][64];
  __shared__ ushort Bs[128][64];
  const int b = blockIdx.y;
  int bid = blockIdx.x;
  if (SWZ) {
    int cpx = gridDim.x >> 3;
    bid = (bid & 7) * cpx + (bid >> 3);
  }
  const int ntiles = N >> 7;
  const int m0 = (bid / ntiles) << 7;
  const int n0 = (bid % ntiles) << 7;
  const ushort* Ab = A + (size_t)b * sA;
  const ushort* Bb = Bm + (size_t)b * sB;

  const int t    = threadIdx.x;
  const int lane = t & 63, w = t >> 6;
  const int wr = w >> 1, wc = w & 1;
  const int r16 = lane & 15, g = lane >> 4;

  const int srow = lane >> 3;
  const int scol = (lane & 7) << 3;

  f32x4 acc[4][4] = {};

  for (int k0 = 0; k0 < K; k0 += 64) {
    #pragma unroll
    for (int j = 0; j < 4; ++j) {
      int row = j * 32 + w * 8 + srow;
      int ar = m0 + row;
      if (MPRED) ar = ar < M ? ar : M - 1;
      gload_lds16(Ab + (size_t)ar * lda + k0 + scol, &As[0][0] + j * 2048 + w * 512);
    }
    #pragma unroll
    for (int j = 0; j < 4; ++j) {
      int row = j * 32 + w * 8 + srow;
      gload_lds16(Bb + (size_t)(n0 + row) * ldb + k0 + scol, &Bs[0][0] + j * 2048 + w * 512);
    }
    __syncthreads();
    #pragma unroll
    for (int kk = 0; kk < 2; ++kk) {
      bf16x8 af[4], bf[4];
      #pragma unroll
      for (int f = 0; f < 4; ++f) {
        af[f] = *reinterpret_cast<const bf16x8*>(&As[wr * 64 + f * 16 + r16][kk * 32 + g * 8]);
        bf[f] = *reinterpret_cast<const bf16x8*>(&Bs[wc * 64 + f * 16 + r16][kk * 32 + g * 8]);
      }
      #pragma unroll
      for (int fr = 0; fr < 4; ++fr)
        #pragma unroll
        for (int fc = 0; fc < 4; ++fc)
          acc[fr][fc] = __builtin_amdgcn_mfma_f32_16x16x32_bf16(af[fr], bf[fc], acc[fr][fc], 0, 0, 0);
    }
    __syncthreads();
  }

  #pragma unroll
  for (int fr = 0; fr < 4; ++fr) {
    int rbase = m0 + wr * 64 + fr * 16 + g * 4;
    #pragma unroll
    for (int r = 0; r < 4; ++r) {
      if (MPRED && (rbase + r >= M)) continue;
      size_t off0 = (size_t)b * sC + (size_t)(rbase + r) * ldc + n0 + wc * 64;
      #pragma unroll
      for (int fc = 0; fc < 4; ++fc) {
        int col = fc * 16 + r16;
        float v = acc[fr][fc][r];
        if (RELU_BIAS) v = fmaxf(v + bias[n0 + wc * 64 + col], 0.0f);
        if (OUT_BF16) reinterpret_cast<ushort*>(C)[off0 + col] = f2b(v);
        else          reinterpret_cast<float*>(C)[off0 + col]  = v;
      }
    }
  }
}

// ---------------- fused pass1: rowsums + col partials + attn_img stats --------
// G bf16 [B][LI][LT]. block = b*4+ch (144 rows each). Outputs:
//   rs_t[b][i] full rowsums; csp[blk][t] col partials; pm/ps[blk][t] online stats.
__global__ __launch_bounds__(256) void gstats_kernel(
    const ushort* __restrict__ G, float* __restrict__ rs_t,
    float* __restrict__ csp, float* __restrict__ pm, float* __restrict__ ps) {
  __shared__ float redm[4][LT];
  __shared__ float reds[4][LT];
  int blk = blockIdx.x;
  int b = blk >> 2, ch = blk & 3;
  int w = threadIdx.x >> 6, lane = threadIdx.x & 63;
  const ushort* g = G + (size_t)b * LI * LT;
  int i0 = ch * 144;
  float c0 = 0.f, c1 = 0.f, c2 = 0.f, c3 = 0.f;
  float m0 = -1e30f, m1 = -1e30f, m2 = -1e30f, m3 = -1e30f;
  float s0 = 0.f, s1 = 0.f, s2 = 0.f, s3 = 0.f;
  for (int k = 0; k < 36; ++k) {
    int i = i0 + k * 4 + w;
    ushort4 u = reinterpret_cast<const ushort4*>(g + (size_t)i * LT)[lane];
    float r0 = fmaxf(b2f(u.x), 0.f), r1 = fmaxf(b2f(u.y), 0.f);
    float r2 = fmaxf(b2f(u.z), 0.f), r3 = fmaxf(b2f(u.w), 0.f);
    c0 += r0; c1 += r1; c2 += r2; c3 += r3;
    float s = r0 + r1 + r2 + r3;
    #pragma unroll
    for (int off = 32; off > 0; off >>= 1) s += __shfl_xor(s, off);
    if (lane == 0) rs_t[b * LI + i] = s;
    float inv = SMOOTHF / (s + EPSF);
    float x0 = r0 * inv, x1 = r1 * inv, x2 = r2 * inv, x3 = r3 * inv;
    float mn;
    mn = fmaxf(m0, x0); s0 = s0 * __expf(m0 - mn) + __expf(x0 - mn); m0 = mn;
    mn = fmaxf(m1, x1); s1 = s1 * __expf(m1 - mn) + __expf(x1 - mn); m1 = mn;
    mn = fmaxf(m2, x2); s2 = s2 * __expf(m2 - mn) + __expf(x2 - mn); m2 = mn;
    mn = fmaxf(m3, x3); s3 = s3 * __expf(m3 - mn) + __expf(x3 - mn); m3 = mn;
  }
  int t = threadIdx.x;
  // col partials
  redm[w][lane * 4 + 0] = c0; redm[w][lane * 4 + 1] = c1;
  redm[w][lane * 4 + 2] = c2; redm[w][lane * 4 + 3] = c3;
  __syncthreads();
  csp[(size_t)blk * LT + t] = redm[0][t] + redm[1][t] + redm[2][t] + redm[3][t];
  __syncthreads();
  // stats merge across waves
  redm[w][lane * 4 + 0] = m0; redm[w][lane * 4 + 1] = m1;
  redm[w][lane * 4 + 2] = m2; redm[w][lane * 4 + 3] = m3;
  reds[w][lane * 4 + 0] = s0; reds[w][lane * 4 + 1] = s1;
  reds[w][lane * 4 + 2] = s2; reds[w][lane * 4 + 3] = s3;
  __syncthreads();
  float mm = fmaxf(fmaxf(redm[0][t], redm[1][t]), fmaxf(redm[2][t], redm[3][t]));
  float ss = reds[0][t] * __expf(redm[0][t] - mm) + reds[1][t] * __expf(redm[1][t] - mm)
           + reds[2][t] * __expf(redm[2][t] - mm) + reds[3][t] * __expf(redm[3][t] - mm);
  pm[(size_t)blk * LT + t] = mm;
  ps[(size_t)blk * LT + t] = ss;
}

// ---------------- combine: rs_i + final attn_img stats ----------------
__global__ __launch_bounds__(256) void combine_kernel(
    const float* __restrict__ csp, const float* __restrict__ pm,
    const float* __restrict__ ps, float* __restrict__ rs_i,
    float* __restrict__ m_out, float* __restrict__ s_out) {
  int b = blockIdx.x, t = threadIdx.x;
  float cs = 0.f;
  #pragma unroll
  for (int q = 0; q < 4; ++q) cs += csp[(size_t)(b * 4 + q) * LT + t];
  rs_i[b * LT + t] = cs;
  float m = -1e30f;
  #pragma unroll
  for (int q = 0; q < 4; ++q) m = fmaxf(m, pm[(size_t)(b * 4 + q) * LT + t]);
  float s = 0.f;
  #pragma unroll
  for (int q = 0; q < 4; ++q)
    s += ps[(size_t)(b * 4 + q) * LT + t] * __expf(pm[(size_t)(b * 4 + q) * LT + t] - m);
  m_out[b * LT + t] = m;
  s_out[b * LT + t] = s;
}

// ---------------- fused pass2: attn_txt + attn_img from one G tile ----------
// block: 64 i-rows x all 256 t. Phase A: row softmax -> attn_txt [b][i][t].
// Phase B: per 64-t subtile, compute+transpose -> attn_img [b][t][i].
__global__ __launch_bounds__(256) void attn_fused_kernel(
    const ushort* __restrict__ G, const float* __restrict__ rs_i,
    const float* __restrict__ rs_t, const float* __restrict__ mi,
    const float* __restrict__ si,
    float* __restrict__ at_f32, ushort* __restrict__ at_b16,
    float* __restrict__ ai_f32, ushort* __restrict__ ai_b16) {
  __shared__ ushort Gs[64][264];     // bf16 tile, +8 pad
  __shared__ float  T[64][65];
  __shared__ float  invl_s[64];
  int b = blockIdx.y, i0 = blockIdx.x * 64;
  int q = threadIdx.x;
  { // load tile: rows coalesced
    int row = q >> 2, c0 = (q & 3) * 64;
    const ushort* src = G + ((size_t)b * LI + i0 + row) * LT + c0;
    #pragma unroll
    for (int e = 0; e < 8; ++e) {
      uint4 v = *reinterpret_cast<const uint4*>(src + e * 8);
      *reinterpret_cast<uint4*>(&Gs[row][c0 + e * 8]) = v;
    }
  }
  if (q < 64) invl_s[q] = SMOOTHF / (rs_t[b * LI + i0 + q] + EPSF);
  __syncthreads();

  // ---- phase A: attn_txt (row softmax over t) ----
  {
    int w = q >> 6, lane = q & 63;
    float4 dv = reinterpret_cast<const float4*>(rs_i + (size_t)b * LT)[lane];
    float i0d = SMOOTHF / (dv.x + EPSF), i1d = SMOOTHF / (dv.y + EPSF);
    float i2d = SMOOTHF / (dv.z + EPSF), i3d = SMOOTHF / (dv.w + EPSF);
    #pragma unroll 4
    for (int rr = 0; rr < 16; ++rr) {
      int row = w * 16 + rr;
      ushort4 gu = *reinterpret_cast<const ushort4*>(&Gs[row][lane * 4]);
      float x0 = fmaxf(b2f(gu.x), 0.f) * i0d;
      float x1 = fmaxf(b2f(gu.y), 0.f) * i1d;
      float x2 = fmaxf(b2f(gu.z), 0.f) * i2d;
      float x3 = fmaxf(b2f(gu.w), 0.f) * i3d;
      float m = fmaxf(fmaxf(x0, x1), fmaxf(x2, x3));
      #pragma unroll
      for (int off = 32; off > 0; off >>= 1) m = fmaxf(m, __shfl_xor(m, off));
      float e0 = __expf(x0 - m), e1 = __expf(x1 - m);
      float e2 = __expf(x2 - m), e3 = __expf(x3 - m);
      float s = e0 + e1 + e2 + e3;
      #pragma unroll
      for (int off = 32; off > 0; off >>= 1) s += __shfl_xor(s, off);
      float inv = 1.0f / s;
      float4 o = make_float4(e0 * inv, e1 * inv, e2 * inv, e3 * inv);
      size_t roff = ((size_t)b * LI + i0 + row) * LT;
      reinterpret_cast<float4*>(at_f32 + roff)[lane] = o;
      reinterpret_cast<ushort4*>(at_b16 + roff)[lane] =
          make_ushort4(f2b(o.x), f2b(o.y), f2b(o.z), f2b(o.w));
    }
  }

  // ---- phase B: attn_img, 4 x (64t x 64i) transposed subtiles ----
  for (int tt = 0; tt < 4; ++tt) {
    __syncthreads();   // T free
    {
      int row = q >> 2;               // i within tile
      int t4  = (q & 3) * 16;         // t within subtile
      float invl = invl_s[row];
      const float* mip = mi + (size_t)b * LT + tt * 64 + t4;
      const float* sip = si + (size_t)b * LT + tt * 64 + t4;
      float mt[16], ist[16];
      #pragma unroll
      for (int e4 = 0; e4 < 4; ++e4) {
        float4 mv = *reinterpret_cast<const float4*>(mip + e4 * 4);
        float4 sv = *reinterpret_cast<const float4*>(sip + e4 * 4);
        mt[e4 * 4 + 0] = mv.x; mt[e4 * 4 + 1] = mv.y;
        mt[e4 * 4 + 2] = mv.z; mt[e4 * 4 + 3] = mv.w;
        ist[e4 * 4 + 0] = 1.0f / sv.x; ist[e4 * 4 + 1] = 1.0f / sv.y;
        ist[e4 * 4 + 2] = 1.0f / sv.z; ist[e4 * 4 + 3] = 1.0f / sv.w;
      }
      #pragma unroll
      for (int u = 0; u < 2; ++u) {
        ushort gu[8];
        *reinterpret_cast<uint4*>(gu) =
            *reinterpret_cast<const uint4*>(&Gs[row][tt * 64 + t4 + u * 8]);
        #pragma unroll
        for (int e = 0; e < 8; ++e) {
          int idx = u * 8 + e;
          float x = fmaxf(b2f(gu[e]), 0.f) * invl;
          T[t4 + idx][row] = __expf(x - mt[idx]) * ist[idx];
        }
      }
    }
    __syncthreads();
    {
      int trow = q >> 2;              // t within subtile
      int i4   = (q & 3) * 16;        // i within tile
      size_t off = ((size_t)b * LT + tt * 64 + trow) * LI + i0 + i4;
      #pragma unroll
      for (int e4 = 0; e4 < 4; ++e4) {
        float4 o = make_float4(T[trow][i4 + e4 * 4], T[trow][i4 + e4 * 4 + 1],
                               T[trow][i4 + e4 * 4 + 2], T[trow][i4 + e4 * 4 + 3]);
        *reinterpret_cast<float4*>(ai_f32 + off + e4 * 4) = o;
        reinterpret_cast<ushort4*>(ai_b16 + off)[e4] =
            make_ushort4(f2b(o.x), f2b(o.y), f2b(o.z), f2b(o.w));
      }
    }
  }
}

// ---------------- launch ----------------
extern "C" void kernel_launch(void* const* d_in, const int* in_sizes, int n_in,
                              void* d_out, int out_size, void* d_ws, size_t ws_size,
                              hipStream_t stream) {
  const float* txt   = (const float*)d_in[0];
  const float* img   = (const float*)d_in[1];
  const float* W_txt = (const float*)d_in[2];
  const float* b_txt = (const float*)d_in[3];
  const float* W_img = (const float*)d_in[4];
  const float* b_img = (const float*)d_in[5];

  float* out          = (float*)d_out;
  float* out_txt      = out;
  float* out_img      = out + (size_t)B_ * LT * HD;
  float* out_attn_img = out_img + (size_t)B_ * LI * HD;
  float* out_attn_txt = out_attn_img + (size_t)B_ * LT * LI;

  char* w = (char*)d_ws;
  auto alloc = [&](size_t bytes) -> char* {
    char* p = w; w += (bytes + 255) & ~(size_t)255; return p;
  };
  ushort* txt_b  = (ushort*)alloc((size_t)B_ * LT * HD * 2);
  ushort* txtT_b = (ushort*)alloc((size_t)B_ * HD * LT * 2);
  ushort* img_b  = (ushort*)alloc((size_t)B_ * LI * HD * 2);
  ushort* imgT_b = (ushort*)alloc((size_t)B_ * HD * LI * 2);
  ushort* Wt_b   = (ushort*)alloc((size_t)HD * HD * 2);
  ushort* Wi_b   = (ushort*)alloc((size_t)HD * HD * 2);
  ushort* Gm_b   = (ushort*)alloc((size_t)B_ * LI * LT * 2);   // G in bf16
  float*  rs_t   = (float*) alloc((size_t)B_ * LI * 4);
  float*  csp    = (float*) alloc((size_t)B_ * 4 * LT * 4);
  float*  pm     = (float*) alloc((size_t)B_ * 4 * LT * 4);
  float*  ps     = (float*) alloc((size_t)B_ * 4 * LT * 4);
  float*  rs_i   = (float*) alloc((size_t)B_ * LT * 4);
  float*  mi     = (float*) alloc((size_t)B_ * LT * 4);
  float*  si     = (float*) alloc((size_t)B_ * LT * 4);
  ushort* ai_b   = (ushort*)alloc((size_t)B_ * LT * LI * 2);
  ushort* at_b   = (ushort*)alloc((size_t)B_ * LI * LT * 2);
  ushort* txtAE  = (ushort*)alloc((size_t)B_ * LT * HD * 2);
  ushort* imgAE  = (ushort*)alloc((size_t)B_ * LI * HD * 2);
  (void)ws_size; (void)in_sizes; (void)n_in; (void)out_size;

  // bf16 conversions (+ transposed context copies for NT AV GEMMs)
  cvtT_kernel<<<dim3((LT / 64) * (HD / 64), B_), 256, 0, stream>>>(txt, txt_b, txtT_b, LT);
  cvtT_kernel<<<dim3((LI / 64) * (HD / 64), B_), 256, 0, stream>>>(img, img_b, imgT_b, LI);
  cvt_bf16_kernel<<<1024, 256, 0, stream>>>(W_txt, Wt_b, HD * HD / 4);
  cvt_bf16_kernel<<<1024, 256, 0, stream>>>(W_img, Wi_b, HD * HD / 4);

  // G[b,i,t] = img[b,i,:].txt[b,t,:]  -> bf16 (NT, M=576 pred)
  dim3 gG(5 * (LT / 128), B_);
  gemm128<true, true, false, false><<<gG, 256, 0, stream>>>(
      img_b, txt_b, nullptr, Gm_b, LI, LT, HD,
      (long)LI * HD, (long)LT * HD, (long)LI * LT, HD, HD, LT);

  // pass1: rowsums + col partials + attn_img online stats (one G read)
  gstats_kernel<<<B_ * 4, 256, 0, stream>>>(Gm_b, rs_t, csp, pm, ps);
  combine_kernel<<<B_, 256, 0, stream>>>(csp, pm, ps, rs_i, mi, si);

  // pass2: attn_txt + attn_img outputs (one G read)
  attn_fused_kernel<<<dim3(LI / 64, B_), 256, 0, stream>>>(
      Gm_b, rs_i, rs_t, mi, si, out_attn_txt, at_b, out_attn_img, ai_b);

  // txtAE = attn_img . img   (NT via imgT_b [HD][LI])
  dim3 g1((LT / 128) * (HD / 128), B_);
  gemm128<false, true, false, false><<<g1, 256, 0, stream>>>(
      ai_b, imgT_b, nullptr, txtAE, LT, HD, LI,
      (long)LT * LI, (long)HD * LI, (long)LT * HD, LI, LI, HD);

  // imgAE = attn_txt . txt   (NT via txtT_b [HD][LT], M=576 pred)
  dim3 g2(5 * (HD / 128), B_);
  gemm128<true, true, false, false><<<g2, 256, 0, stream>>>(
      at_b, txtT_b, nullptr, imgAE, LI, HD, LT,
      (long)LI * LT, (long)HD * LT, (long)LI * HD, LT, LT, HD);

  // FC heads flattened over batch (shared W): relu(x @ W^T + b), NT, XCD swizzle
  dim3 gf1((B_ * LT / 128) * (HD / 128), 1);
  gemm128<false, false, true, true><<<gf1, 256, 0, stream>>>(
      txtAE, Wt_b, b_txt, out_txt, B_ * LT, HD, HD,
      0L, 0L, 0L, HD, HD, HD);
  dim3 gf2((B_ * LI / 128) * (HD / 128), 1);
  gemm128<false, false, true, true><<<gf2, 256, 0, stream>>>(
      imgAE, Wi_b, b_img, out_img, B_ * LI, HD, HD,
      0L, 0L, 0L, HD, HD, HD);
}

// Round 7
// 805.060 us; speedup vs baseline: 1.2029x; 1.1717x over previous
//
#include <hip/hip_runtime.h>
#include <hip/hip_bf16.h>
#include <stdint.h>

#define B_   128
#define LT   256
#define LI   576
#define HD   1024
#define SMOOTHF 9.0f
#define EPSF 1e-8f

typedef __bf16 bf16x8 __attribute__((ext_vector_type(8)));
typedef float  f32x4  __attribute__((ext_vector_type(4)));

__device__ inline ushort f2b(float f) {
  uint32_t u = __float_as_uint(f);
  u += 0x7FFFu + ((u >> 16) & 1u);   // RNE
  return (ushort)(u >> 16);
}
__device__ inline float b2f(ushort u) {
  return __uint_as_float((uint32_t)u << 16);
}

// async global->LDS, 16B per lane. LDS dest is wave-uniform base + lane*16.
__device__ __forceinline__ void gload_lds16(const ushort* g, ushort* l) {
  __builtin_amdgcn_global_load_lds(
      (const __attribute__((address_space(1))) unsigned int*)(g),
      (__attribute__((address_space(3))) unsigned int*)(l),
      16, 0, 0);
}

// ---------------- fp32 -> bf16 (vectorized) ----------------
__global__ __launch_bounds__(256) void cvt_bf16_kernel(
    const float* __restrict__ in, ushort* __restrict__ out, int n4) {
  int idx = blockIdx.x * blockDim.x + threadIdx.x;
  int stride = gridDim.x * blockDim.x;
  for (int i = idx; i < n4; i += stride) {
    float4 v = reinterpret_cast<const float4*>(in)[i];
    ushort4 o = make_ushort4(f2b(v.x), f2b(v.y), f2b(v.z), f2b(v.w));
    reinterpret_cast<ushort4*>(out)[i] = o;
  }
}

// ---------------- m97-structure GEMM: 128x128 tile, BK=64, 4 waves ----------
// C[m,n] = sum_k A[m,k]*B'[k,n].  A always [M,K] row-major (K contig).
//  BT=false: B [N,K] row-major -> global_load_lds staging.
//  BT=true : B [K,N] row-major -> transpose-staged, 2-way-free ds_writes.
template<bool BT, bool MPRED, bool OUT_BF16, bool RELU_BIAS, bool SWZ>
__global__ __launch_bounds__(256)
void gemm128(const ushort* __restrict__ A, const ushort* __restrict__ Bm,
             const float* __restrict__ bias, void* __restrict__ C,
             int M, int N, int K,
             long sA, long sB, long sC, int lda, int ldb, int ldc)
{
  __shared__ ushort As[128][64];
  __shared__ ushort Bs[128][64];
  const int b = blockIdx.y;
  int bid = blockIdx.x;
  if (SWZ) {                                  // XCD swizzle (nwg % 8 == 0)
    int cpx = gridDim.x >> 3;
    bid = (bid & 7) * cpx + (bid >> 3);
  }
  const int ntiles = N >> 7;
  const int m0 = (bid / ntiles) << 7;
  const int n0 = (bid % ntiles) << 7;
  const ushort* Ab = A + (size_t)b * sA;
  const ushort* Bb = Bm + (size_t)b * sB;

  const int t    = threadIdx.x;
  const int lane = t & 63, w = t >> 6;
  const int wr = w >> 1, wc = w & 1;          // 2x2 waves, 64x64 out each
  const int r16 = lane & 15, g = lane >> 4;

  const int srow = lane >> 3;                 // 0..7
  const int scol = (lane & 7) << 3;           // 0..56

  f32x4 acc[4][4] = {};

  for (int k0 = 0; k0 < K; k0 += 64) {
    #pragma unroll
    for (int j = 0; j < 4; ++j) {
      int row = j * 32 + w * 8 + srow;
      int ar = m0 + row;
      if (MPRED) ar = ar < M ? ar : M - 1;
      gload_lds16(Ab + (size_t)ar * lda + k0 + scol, &As[0][0] + j * 2048 + w * 512);
    }
    if (!BT) {
      #pragma unroll
      for (int j = 0; j < 4; ++j) {
        int row = j * 32 + w * 8 + srow;
        gload_lds16(Bb + (size_t)(n0 + row) * ldb + k0 + scol, &Bs[0][0] + j * 2048 + w * 512);
      }
    } else {
      // B[k][n] -> Bs[n][k]; lane = (k-pair kp 0..31) x (n-octet gg 0..7).
      // Per-instr ds_write banks: kp spans all 32 banks, 2 lanes each = free.
      const int kp = t & 31;
      const int gg = t >> 5;
      uint32_t* B32 = reinterpret_cast<uint32_t*>(&Bs[0][0]);
      #pragma unroll
      for (int h = 0; h < 2; ++h) {
        int nc = (gg + h * 8) << 3;           // 0..120
        const ushort* s0 = Bb + (size_t)(k0 + 2 * kp) * ldb + n0 + nc;
        uint4 u0 = *reinterpret_cast<const uint4*>(s0);
        uint4 u1 = *reinterpret_cast<const uint4*>(s0 + ldb);
        ushort e0[8], e1[8];
        *reinterpret_cast<uint4*>(e0) = u0;
        *reinterpret_cast<uint4*>(e1) = u1;
        #pragma unroll
        for (int e = 0; e < 8; ++e)
          B32[(size_t)(nc + e) * 32 + kp] = (uint32_t)e0[e] | ((uint32_t)e1[e] << 16);
      }
    }
    __syncthreads();
    #pragma unroll
    for (int kk = 0; kk < 2; ++kk) {
      bf16x8 af[4], bf[4];
      #pragma unroll
      for (int f = 0; f < 4; ++f) {
        af[f] = *reinterpret_cast<const bf16x8*>(&As[wr * 64 + f * 16 + r16][kk * 32 + g * 8]);
        bf[f] = *reinterpret_cast<const bf16x8*>(&Bs[wc * 64 + f * 16 + r16][kk * 32 + g * 8]);
      }
      #pragma unroll
      for (int fr = 0; fr < 4; ++fr)
        #pragma unroll
        for (int fc = 0; fc < 4; ++fc)
          acc[fr][fc] = __builtin_amdgcn_mfma_f32_16x16x32_bf16(af[fr], bf[fc], acc[fr][fc], 0, 0, 0);
    }
    __syncthreads();
  }

  // epilogue: C/D layout col=lane&15, row=(lane>>4)*4+reg [m89-verified]
  #pragma unroll
  for (int fr = 0; fr < 4; ++fr) {
    int rbase = m0 + wr * 64 + fr * 16 + g * 4;
    #pragma unroll
    for (int r = 0; r < 4; ++r) {
      if (MPRED && (rbase + r >= M)) continue;
      size_t off0 = (size_t)b * sC + (size_t)(rbase + r) * ldc + n0 + wc * 64;
      #pragma unroll
      for (int fc = 0; fc < 4; ++fc) {
        int col = fc * 16 + r16;
        float v = acc[fr][fc][r];
        if (RELU_BIAS) v = fmaxf(v + bias[n0 + wc * 64 + col], 0.0f);
        if (OUT_BF16) reinterpret_cast<ushort*>(C)[off0 + col] = f2b(v);
        else          reinterpret_cast<float*>(C)[off0 + col]  = v;
      }
    }
  }
}

// ---------------- fused pass1: rowsums + col partials + attn_img stats --------
__global__ __launch_bounds__(256) void gstats_kernel(
    const ushort* __restrict__ G, float* __restrict__ rs_t,
    float* __restrict__ csp, float* __restrict__ pm, float* __restrict__ ps) {
  __shared__ float redm[4][LT];
  __shared__ float reds[4][LT];
  int blk = blockIdx.x;
  int b = blk >> 2, ch = blk & 3;
  int w = threadIdx.x >> 6, lane = threadIdx.x & 63;
  const ushort* g = G + (size_t)b * LI * LT;
  int i0 = ch * 144;
  float c0 = 0.f, c1 = 0.f, c2 = 0.f, c3 = 0.f;
  float m0 = -1e30f, m1 = -1e30f, m2 = -1e30f, m3 = -1e30f;
  float s0 = 0.f, s1 = 0.f, s2 = 0.f, s3 = 0.f;
  for (int k = 0; k < 36; ++k) {
    int i = i0 + k * 4 + w;
    ushort4 u = reinterpret_cast<const ushort4*>(g + (size_t)i * LT)[lane];
    float r0 = fmaxf(b2f(u.x), 0.f), r1 = fmaxf(b2f(u.y), 0.f);
    float r2 = fmaxf(b2f(u.z), 0.f), r3 = fmaxf(b2f(u.w), 0.f);
    c0 += r0; c1 += r1; c2 += r2; c3 += r3;
    float s = r0 + r1 + r2 + r3;
    #pragma unroll
    for (int off = 32; off > 0; off >>= 1) s += __shfl_xor(s, off);
    if (lane == 0) rs_t[b * LI + i] = s;
    float inv = SMOOTHF / (s + EPSF);
    float x0 = r0 * inv, x1 = r1 * inv, x2 = r2 * inv, x3 = r3 * inv;
    float mn;
    mn = fmaxf(m0, x0); s0 = s0 * __expf(m0 - mn) + __expf(x0 - mn); m0 = mn;
    mn = fmaxf(m1, x1); s1 = s1 * __expf(m1 - mn) + __expf(x1 - mn); m1 = mn;
    mn = fmaxf(m2, x2); s2 = s2 * __expf(m2 - mn) + __expf(x2 - mn); m2 = mn;
    mn = fmaxf(m3, x3); s3 = s3 * __expf(m3 - mn) + __expf(x3 - mn); m3 = mn;
  }
  int t = threadIdx.x;
  redm[w][lane * 4 + 0] = c0; redm[w][lane * 4 + 1] = c1;
  redm[w][lane * 4 + 2] = c2; redm[w][lane * 4 + 3] = c3;
  __syncthreads();
  csp[(size_t)blk * LT + t] = redm[0][t] + redm[1][t] + redm[2][t] + redm[3][t];
  __syncthreads();
  redm[w][lane * 4 + 0] = m0; redm[w][lane * 4 + 1] = m1;
  redm[w][lane * 4 + 2] = m2; redm[w][lane * 4 + 3] = m3;
  reds[w][lane * 4 + 0] = s0; reds[w][lane * 4 + 1] = s1;
  reds[w][lane * 4 + 2] = s2; reds[w][lane * 4 + 3] = s3;
  __syncthreads();
  float mm = fmaxf(fmaxf(redm[0][t], redm[1][t]), fmaxf(redm[2][t], redm[3][t]));
  float ss = reds[0][t] * __expf(redm[0][t] - mm) + reds[1][t] * __expf(redm[1][t] - mm)
           + reds[2][t] * __expf(redm[2][t] - mm) + reds[3][t] * __expf(redm[3][t] - mm);
  pm[(size_t)blk * LT + t] = mm;
  ps[(size_t)blk * LT + t] = ss;
}

// ---------------- combine: rs_i + final attn_img stats ----------------
__global__ __launch_bounds__(256) void combine_kernel(
    const float* __restrict__ csp, const float* __restrict__ pm,
    const float* __restrict__ ps, float* __restrict__ rs_i,
    float* __restrict__ m_out, float* __restrict__ s_out) {
  int b = blockIdx.x, t = threadIdx.x;
  float cs = 0.f;
  #pragma unroll
  for (int q = 0; q < 4; ++q) cs += csp[(size_t)(b * 4 + q) * LT + t];
  rs_i[b * LT + t] = cs;
  float m = -1e30f;
  #pragma unroll
  for (int q = 0; q < 4; ++q) m = fmaxf(m, pm[(size_t)(b * 4 + q) * LT + t]);
  float s = 0.f;
  #pragma unroll
  for (int q = 0; q < 4; ++q)
    s += ps[(size_t)(b * 4 + q) * LT + t] * __expf(pm[(size_t)(b * 4 + q) * LT + t] - m);
  m_out[b * LT + t] = m;
  s_out[b * LT + t] = s;
}

// ---------------- fused pass2: attn_txt + attn_img from one G tile ----------
__global__ __launch_bounds__(256) void attn_fused_kernel(
    const ushort* __restrict__ G, const float* __restrict__ rs_i,
    const float* __restrict__ rs_t, const float* __restrict__ mi,
    const float* __restrict__ si,
    float* __restrict__ at_f32, ushort* __restrict__ at_b16,
    float* __restrict__ ai_f32, ushort* __restrict__ ai_b16) {
  __shared__ ushort Gs[64][264];     // bf16 tile, +8 pad
  __shared__ float  T[64][65];
  __shared__ float  invl_s[64];
  int b = blockIdx.y, i0 = blockIdx.x * 64;
  int q = threadIdx.x;
  { // load tile: rows coalesced
    int row = q >> 2, c0 = (q & 3) * 64;
    const ushort* src = G + ((size_t)b * LI + i0 + row) * LT + c0;
    #pragma unroll
    for (int e = 0; e < 8; ++e) {
      uint4 v = *reinterpret_cast<const uint4*>(src + e * 8);
      *reinterpret_cast<uint4*>(&Gs[row][c0 + e * 8]) = v;
    }
  }
  if (q < 64) invl_s[q] = SMOOTHF / (rs_t[b * LI + i0 + q] + EPSF);
  __syncthreads();

  // ---- phase A: attn_txt (row softmax over t) ----
  {
    int w = q >> 6, lane = q & 63;
    float4 dv = reinterpret_cast<const float4*>(rs_i + (size_t)b * LT)[lane];
    float i0d = SMOOTHF / (dv.x + EPSF), i1d = SMOOTHF / (dv.y + EPSF);
    float i2d = SMOOTHF / (dv.z + EPSF), i3d = SMOOTHF / (dv.w + EPSF);
    #pragma unroll 4
    for (int rr = 0; rr < 16; ++rr) {
      int row = w * 16 + rr;
      ushort4 gu = *reinterpret_cast<const ushort4*>(&Gs[row][lane * 4]);
      float x0 = fmaxf(b2f(gu.x), 0.f) * i0d;
      float x1 = fmaxf(b2f(gu.y), 0.f) * i1d;
      float x2 = fmaxf(b2f(gu.z), 0.f) * i2d;
      float x3 = fmaxf(b2f(gu.w), 0.f) * i3d;
      float m = fmaxf(fmaxf(x0, x1), fmaxf(x2, x3));
      #pragma unroll
      for (int off = 32; off > 0; off >>= 1) m = fmaxf(m, __shfl_xor(m, off));
      float e0 = __expf(x0 - m), e1 = __expf(x1 - m);
      float e2 = __expf(x2 - m), e3 = __expf(x3 - m);
      float s = e0 + e1 + e2 + e3;
      #pragma unroll
      for (int off = 32; off > 0; off >>= 1) s += __shfl_xor(s, off);
      float inv = 1.0f / s;
      float4 o = make_float4(e0 * inv, e1 * inv, e2 * inv, e3 * inv);
      size_t roff = ((size_t)b * LI + i0 + row) * LT;
      reinterpret_cast<float4*>(at_f32 + roff)[lane] = o;
      reinterpret_cast<ushort4*>(at_b16 + roff)[lane] =
          make_ushort4(f2b(o.x), f2b(o.y), f2b(o.z), f2b(o.w));
    }
  }

  // ---- phase B: attn_img, 4 x (64t x 64i) transposed subtiles ----
  for (int tt = 0; tt < 4; ++tt) {
    __syncthreads();
    {
      int row = q >> 2;
      int t4  = (q & 3) * 16;
      float invl = invl_s[row];
      const float* mip = mi + (size_t)b * LT + tt * 64 + t4;
      const float* sip = si + (size_t)b * LT + tt * 64 + t4;
      float mt[16], ist[16];
      #pragma unroll
      for (int e4 = 0; e4 < 4; ++e4) {
        float4 mv = *reinterpret_cast<const float4*>(mip + e4 * 4);
        float4 sv = *reinterpret_cast<const float4*>(sip + e4 * 4);
        mt[e4 * 4 + 0] = mv.x; mt[e4 * 4 + 1] = mv.y;
        mt[e4 * 4 + 2] = mv.z; mt[e4 * 4 + 3] = mv.w;
        ist[e4 * 4 + 0] = 1.0f / sv.x; ist[e4 * 4 + 1] = 1.0f / sv.y;
        ist[e4 * 4 + 2] = 1.0f / sv.z; ist[e4 * 4 + 3] = 1.0f / sv.w;
      }
      #pragma unroll
      for (int u = 0; u < 2; ++u) {
        ushort gu[8];
        *reinterpret_cast<uint4*>(gu) =
            *reinterpret_cast<const uint4*>(&Gs[row][tt * 64 + t4 + u * 8]);
        #pragma unroll
        for (int e = 0; e < 8; ++e) {
          int idx = u * 8 + e;
          float x = fmaxf(b2f(gu[e]), 0.f) * invl;
          T[t4 + idx][row] = __expf(x - mt[idx]) * ist[idx];
        }
      }
    }
    __syncthreads();
    {
      int trow = q >> 2;
      int i4   = (q & 3) * 16;
      size_t off = ((size_t)b * LT + tt * 64 + trow) * LI + i0 + i4;
      #pragma unroll
      for (int e4 = 0; e4 < 4; ++e4) {
        float4 o = make_float4(T[trow][i4 + e4 * 4], T[trow][i4 + e4 * 4 + 1],
                               T[trow][i4 + e4 * 4 + 2], T[trow][i4 + e4 * 4 + 3]);
        *reinterpret_cast<float4*>(ai_f32 + off + e4 * 4) = o;
        reinterpret_cast<ushort4*>(ai_b16 + off)[e4] =
            make_ushort4(f2b(o.x), f2b(o.y), f2b(o.z), f2b(o.w));
      }
    }
  }
}

// ---------------- launch ----------------
extern "C" void kernel_launch(void* const* d_in, const int* in_sizes, int n_in,
                              void* d_out, int out_size, void* d_ws, size_t ws_size,
                              hipStream_t stream) {
  const float* txt   = (const float*)d_in[0];
  const float* img   = (const float*)d_in[1];
  const float* W_txt = (const float*)d_in[2];
  const float* b_txt = (const float*)d_in[3];
  const float* W_img = (const float*)d_in[4];
  const float* b_img = (const float*)d_in[5];

  float* out          = (float*)d_out;
  float* out_txt      = out;
  float* out_img      = out + (size_t)B_ * LT * HD;
  float* out_attn_img = out_img + (size_t)B_ * LI * HD;
  float* out_attn_txt = out_attn_img + (size_t)B_ * LT * LI;

  char* w = (char*)d_ws;
  auto alloc = [&](size_t bytes) -> char* {
    char* p = w; w += (bytes + 255) & ~(size_t)255; return p;
  };
  ushort* txt_b  = (ushort*)alloc((size_t)B_ * LT * HD * 2);
  ushort* img_b  = (ushort*)alloc((size_t)B_ * LI * HD * 2);
  ushort* Wt_b   = (ushort*)alloc((size_t)HD * HD * 2);
  ushort* Wi_b   = (ushort*)alloc((size_t)HD * HD * 2);
  ushort* Gm_b   = (ushort*)alloc((size_t)B_ * LI * LT * 2);
  float*  rs_t   = (float*) alloc((size_t)B_ * LI * 4);
  float*  csp    = (float*) alloc((size_t)B_ * 4 * LT * 4);
  float*  pm     = (float*) alloc((size_t)B_ * 4 * LT * 4);
  float*  ps     = (float*) alloc((size_t)B_ * 4 * LT * 4);
  float*  rs_i   = (float*) alloc((size_t)B_ * LT * 4);
  float*  mi     = (float*) alloc((size_t)B_ * LT * 4);
  float*  si     = (float*) alloc((size_t)B_ * LT * 4);
  ushort* ai_b   = (ushort*)alloc((size_t)B_ * LT * LI * 2);
  ushort* at_b   = (ushort*)alloc((size_t)B_ * LI * LT * 2);
  ushort* txtAE  = (ushort*)alloc((size_t)B_ * LT * HD * 2);
  ushort* Pt     = (ushort*)alloc((size_t)B_ * HD * LT * 2);   // W_img . txt^T
  (void)ws_size; (void)in_sizes; (void)n_in; (void)out_size;   // ~453 MB

  // bf16 conversions (plain — no transposed copies)
  cvt_bf16_kernel<<<2048, 256, 0, stream>>>(txt, txt_b, B_ * LT * HD / 4);
  cvt_bf16_kernel<<<2048, 256, 0, stream>>>(img, img_b, B_ * LI * HD / 4);
  cvt_bf16_kernel<<<1024, 256, 0, stream>>>(W_txt, Wt_b, HD * HD / 4);
  cvt_bf16_kernel<<<1024, 256, 0, stream>>>(W_img, Wi_b, HD * HD / 4);

  // G[b,i,t] = img[b,i,:].txt[b,t,:]  -> bf16 (NT, M=576 pred)
  dim3 gG(5 * (LT / 128), B_);
  gemm128<false, true, true, false, false><<<gG, 256, 0, stream>>>(
      img_b, txt_b, nullptr, Gm_b, LI, LT, HD,
      (long)LI * HD, (long)LT * HD, (long)LI * LT, HD, HD, LT);

  // pass1: rowsums + col partials + attn_img online stats (one G read)
  gstats_kernel<<<B_ * 4, 256, 0, stream>>>(Gm_b, rs_t, csp, pm, ps);
  combine_kernel<<<B_, 256, 0, stream>>>(csp, pm, ps, rs_i, mi, si);

  // pass2: attn_txt + attn_img outputs (one G read)
  attn_fused_kernel<<<dim3(LI / 64, B_), 256, 0, stream>>>(
      Gm_b, rs_i, rs_t, mi, si, out_attn_txt, at_b, out_attn_img, ai_b);

  // Pt[b] = W_img . txt[b]^T  (NT: A=W_img [O][H], B=txt_b [Lt][H]) -> [O][Lt] bf16
  dim3 gP((HD / 128) * (LT / 128), B_);
  gemm128<false, false, true, false, false><<<gP, 256, 0, stream>>>(
      Wi_b, txt_b, nullptr, Pt, HD, LT, HD,
      0L, (long)LT * HD, (long)HD * LT, HD, HD, LT);

  // txtAE = attn_img . img   (BT: B=img [K=LI][N=HD], transpose-staged)
  dim3 g1((LT / 128) * (HD / 128), B_);
  gemm128<true, false, true, false, false><<<g1, 256, 0, stream>>>(
      ai_b, img_b, nullptr, txtAE, LT, HD, LI,
      (long)LT * LI, (long)LI * HD, (long)LT * HD, LI, HD, HD);

  // FC txt head flattened over batch: relu(txtAE @ Wt^T + b), NT, XCD swizzle
  dim3 gf1((B_ * LT / 128) * (HD / 128), 1);
  gemm128<false, false, false, true, true><<<gf1, 256, 0, stream>>>(
      txtAE, Wt_b, b_txt, out_txt, B_ * LT, HD, HD,
      0L, 0L, 0L, HD, HD, HD);

  // out_img = relu(attn_txt . Pt^T + b_img)  (NT: A=at_b [Li][Lt], B=Pt [O][Lt])
  dim3 g2(5 * (HD / 128), B_);
  gemm128<false, true, false, true, false><<<g2, 256, 0, stream>>>(
      at_b, Pt, b_img, out_img, LI, HD, LT,
      (long)LI * LT, (long)HD * LT, (long)LI * HD, LT, LT, HD);
}

// Round 8
// 789.385 us; speedup vs baseline: 1.2268x; 1.0199x over previous
//
#include <hip/hip_runtime.h>
#include <hip/hip_bf16.h>
#include <stdint.h>

#define B_   128
#define LT   256
#define LI   576
#define HD   1024
#define SMOOTHF 9.0f
#define EPSF 1e-8f

typedef __bf16 bf16x8 __attribute__((ext_vector_type(8)));
typedef float  f32x4  __attribute__((ext_vector_type(4)));

__device__ inline ushort f2b(float f) {
  uint32_t u = __float_as_uint(f);
  u += 0x7FFFu + ((u >> 16) & 1u);   // RNE
  return (ushort)(u >> 16);
}
__device__ inline float b2f(ushort u) {
  return __uint_as_float((uint32_t)u << 16);
}

// async global->LDS, 16B per lane. LDS dest is wave-uniform base + lane*16.
__device__ __forceinline__ void gload_lds16(const ushort* g, ushort* l) {
  __builtin_amdgcn_global_load_lds(
      (const __attribute__((address_space(1))) unsigned int*)(g),
      (__attribute__((address_space(3))) unsigned int*)(l),
      16, 0, 0);
}

// ---------------- fp32 -> bf16 (vectorized) ----------------
__global__ __launch_bounds__(256) void cvt_bf16_kernel(
    const float* __restrict__ in, ushort* __restrict__ out, int n4) {
  int idx = blockIdx.x * blockDim.x + threadIdx.x;
  int stride = gridDim.x * blockDim.x;
  for (int i = idx; i < n4; i += stride) {
    float4 v = reinterpret_cast<const float4*>(in)[i];
    ushort4 o = make_ushort4(f2b(v.x), f2b(v.y), f2b(v.z), f2b(v.w));
    reinterpret_cast<ushort4*>(out)[i] = o;
  }
}

// ---------------- m97-structure GEMM: 128x128 tile, BK=64, 4 waves ----------
// C[m,n] = sum_k A[m,k]*B'[k,n].  A always [M,K] row-major (K contig).
//  BT=false: B [N,K] row-major -> global_load_lds staging.
//  BT=true : B [K,N] row-major -> transpose-staged, 2-way-free ds_writes.
template<bool BT, bool MPRED, bool OUT_BF16, bool RELU_BIAS, bool SWZ>
__global__ __launch_bounds__(256)
void gemm128(const ushort* __restrict__ A, const ushort* __restrict__ Bm,
             const float* __restrict__ bias, void* __restrict__ C,
             int M, int N, int K,
             long sA, long sB, long sC, int lda, int ldb, int ldc)
{
  __shared__ ushort As[128][64];
  __shared__ ushort Bs[128][64];
  const int b = blockIdx.y;
  int bid = blockIdx.x;
  if (SWZ) {                                  // XCD swizzle (nwg % 8 == 0)
    int cpx = gridDim.x >> 3;
    bid = (bid & 7) * cpx + (bid >> 3);
  }
  const int ntiles = N >> 7;
  const int m0 = (bid / ntiles) << 7;
  const int n0 = (bid % ntiles) << 7;
  const ushort* Ab = A + (size_t)b * sA;
  const ushort* Bb = Bm + (size_t)b * sB;

  const int t    = threadIdx.x;
  const int lane = t & 63, w = t >> 6;
  const int wr = w >> 1, wc = w & 1;          // 2x2 waves, 64x64 out each
  const int r16 = lane & 15, g = lane >> 4;

  const int srow = lane >> 3;                 // 0..7
  const int scol = (lane & 7) << 3;           // 0..56

  f32x4 acc[4][4] = {};

  for (int k0 = 0; k0 < K; k0 += 64) {
    #pragma unroll
    for (int j = 0; j < 4; ++j) {
      int row = j * 32 + w * 8 + srow;
      int ar = m0 + row;
      if (MPRED) ar = ar < M ? ar : M - 1;
      gload_lds16(Ab + (size_t)ar * lda + k0 + scol, &As[0][0] + j * 2048 + w * 512);
    }
    if (!BT) {
      #pragma unroll
      for (int j = 0; j < 4; ++j) {
        int row = j * 32 + w * 8 + srow;
        gload_lds16(Bb + (size_t)(n0 + row) * ldb + k0 + scol, &Bs[0][0] + j * 2048 + w * 512);
      }
    } else {
      // B[k][n] -> Bs[n][k]; lane = (k-pair kp 0..31) x (n-octet gg 0..7).
      const int kp = t & 31;
      const int gg = t >> 5;
      uint32_t* B32 = reinterpret_cast<uint32_t*>(&Bs[0][0]);
      #pragma unroll
      for (int h = 0; h < 2; ++h) {
        int nc = (gg + h * 8) << 3;           // 0..120
        const ushort* s0 = Bb + (size_t)(k0 + 2 * kp) * ldb + n0 + nc;
        uint4 u0 = *reinterpret_cast<const uint4*>(s0);
        uint4 u1 = *reinterpret_cast<const uint4*>(s0 + ldb);
        ushort e0[8], e1[8];
        *reinterpret_cast<uint4*>(e0) = u0;
        *reinterpret_cast<uint4*>(e1) = u1;
        #pragma unroll
        for (int e = 0; e < 8; ++e)
          B32[(size_t)(nc + e) * 32 + kp] = (uint32_t)e0[e] | ((uint32_t)e1[e] << 16);
      }
    }
    __syncthreads();
    #pragma unroll
    for (int kk = 0; kk < 2; ++kk) {
      bf16x8 af[4], bf[4];
      #pragma unroll
      for (int f = 0; f < 4; ++f) {
        af[f] = *reinterpret_cast<const bf16x8*>(&As[wr * 64 + f * 16 + r16][kk * 32 + g * 8]);
        bf[f] = *reinterpret_cast<const bf16x8*>(&Bs[wc * 64 + f * 16 + r16][kk * 32 + g * 8]);
      }
      #pragma unroll
      for (int fr = 0; fr < 4; ++fr)
        #pragma unroll
        for (int fc = 0; fc < 4; ++fc)
          acc[fr][fc] = __builtin_amdgcn_mfma_f32_16x16x32_bf16(af[fr], bf[fc], acc[fr][fc], 0, 0, 0);
    }
    __syncthreads();
  }

  // epilogue: C/D layout col=lane&15, row=(lane>>4)*4+reg [m89-verified]
  #pragma unroll
  for (int fr = 0; fr < 4; ++fr) {
    int rbase = m0 + wr * 64 + fr * 16 + g * 4;
    #pragma unroll
    for (int r = 0; r < 4; ++r) {
      if (MPRED && (rbase + r >= M)) continue;
      size_t off0 = (size_t)b * sC + (size_t)(rbase + r) * ldc + n0 + wc * 64;
      #pragma unroll
      for (int fc = 0; fc < 4; ++fc) {
        int col = fc * 16 + r16;
        float v = acc[fr][fc][r];
        if (RELU_BIAS) v = fmaxf(v + bias[n0 + wc * 64 + col], 0.0f);
        if (OUT_BF16) reinterpret_cast<ushort*>(C)[off0 + col] = f2b(v);
        else          reinterpret_cast<float*>(C)[off0 + col]  = v;
      }
    }
  }
}

// ---------------- 256x256 tile, BK=64, 8 waves, counted-vmcnt 2-phase --------
// T3-minimum recipe (catalog): dbuf LDS, stage t+1 before compute t,
// vmcnt(8) (tail 0), raw s_barrier (no compiler vmcnt(0) drain), setprio(1).
// Safety: stage at iter t targets buf[cur^1], whose previous tenant (tile t-1)
// was fully read before iter t-1's end barrier -> no read/write race.
// NT (both-operand K-contig) only; M % 256 == 0, N % 256 == 0, K % 64 == 0.
template<bool OUT_BF16, bool RELU_BIAS>
__global__ __launch_bounds__(512, 2)
void gemm256(const ushort* __restrict__ A, const ushort* __restrict__ Bm,
             const float* __restrict__ bias, void* __restrict__ C,
             int N, int K, int lda, int ldb, int ldc)
{
  extern __shared__ ushort lds[];             // [2][256][64] A  +  [2][256][64] B
  int bid = blockIdx.x;
  {                                           // XCD swizzle (nwg % 8 == 0)
    int cpx = gridDim.x >> 3;
    bid = (bid & 7) * cpx + (bid >> 3);
  }
  const int ntiles = N >> 8;
  const int m0 = (bid / ntiles) << 8;
  const int n0 = (bid % ntiles) << 8;

  const int t    = threadIdx.x;
  const int lane = t & 63, w = t >> 6;        // 8 waves
  const int wr = w >> 2, wc = w & 3;          // 2x4 wave grid, 128x64 out each
  const int r16 = lane & 15, g = lane >> 4;
  const int srow = lane >> 3;                 // 0..7
  const int scol = (lane & 7) << 3;           // 0..56

  const ushort* gA0 = A  + (size_t)m0 * lda;
  const ushort* gB0 = Bm + (size_t)n0 * ldb;

  f32x4 acc[8][4] = {};

  const int NT = K >> 6;

  // stage tile kt into buffer buf: 4 A-segments + 4 B-segments per wave
  auto STAGE = [&](int buf, int kt) {
    const ushort* gA = gA0 + kt * 64;
    const ushort* gB = gB0 + kt * 64;
    ushort* lA = lds + buf * 16384;
    ushort* lB = lds + 32768 + buf * 16384;
    #pragma unroll
    for (int j = 0; j < 4; ++j) {
      int row = j * 64 + w * 8 + srow;
      gload_lds16(gA + (size_t)row * lda + scol, lA + j * 4096 + w * 512);
      gload_lds16(gB + (size_t)row * ldb + scol, lB + j * 4096 + w * 512);
    }
  };

  STAGE(0, 0);
  for (int kt = 0; kt < NT; ++kt) {
    const int cur = kt & 1;
    if (kt + 1 < NT) {
      STAGE(cur ^ 1, kt + 1);
      asm volatile("s_waitcnt vmcnt(8)" ::: "memory");   // tile kt landed; kt+1 in flight
    } else {
      asm volatile("s_waitcnt vmcnt(0)" ::: "memory");   // tail drain
    }
    __builtin_amdgcn_sched_barrier(0);
    __builtin_amdgcn_s_barrier();                        // all waves' tile-kt data visible
    __builtin_amdgcn_sched_barrier(0);

    const ushort* Abuf = lds + cur * 16384;
    const ushort* Bbuf = lds + 32768 + cur * 16384;
    __builtin_amdgcn_s_setprio(1);
    #pragma unroll
    for (int kk = 0; kk < 2; ++kk) {
      bf16x8 bfr[4];
      #pragma unroll
      for (int c = 0; c < 4; ++c)
        bfr[c] = *reinterpret_cast<const bf16x8*>(
            Bbuf + (size_t)(wc * 64 + c * 16 + r16) * 64 + kk * 32 + g * 8);
      #pragma unroll
      for (int f = 0; f < 8; ++f) {
        bf16x8 af = *reinterpret_cast<const bf16x8*>(
            Abuf + (size_t)(wr * 128 + f * 16 + r16) * 64 + kk * 32 + g * 8);
        #pragma unroll
        for (int c = 0; c < 4; ++c)
          acc[f][c] = __builtin_amdgcn_mfma_f32_16x16x32_bf16(af, bfr[c], acc[f][c], 0, 0, 0);
      }
    }
    __builtin_amdgcn_s_setprio(0);
    __builtin_amdgcn_sched_barrier(0);
    __builtin_amdgcn_s_barrier();                        // reads done -> next stage safe
    __builtin_amdgcn_sched_barrier(0);
  }

  // epilogue: C/D layout col=lane&15, row=(lane>>4)*4+reg [m89-verified]
  #pragma unroll
  for (int f = 0; f < 8; ++f) {
    int rbase = m0 + wr * 128 + f * 16 + g * 4;
    #pragma unroll
    for (int rr = 0; rr < 4; ++rr) {
      size_t off0 = (size_t)(rbase + rr) * ldc + n0 + wc * 64;
      #pragma unroll
      for (int c = 0; c < 4; ++c) {
        int col = c * 16 + r16;
        float v = acc[f][c][rr];
        if (RELU_BIAS) v = fmaxf(v + bias[n0 + wc * 64 + col], 0.0f);
        if (OUT_BF16) reinterpret_cast<ushort*>(C)[off0 + col] = f2b(v);
        else          reinterpret_cast<float*>(C)[off0 + col]  = v;
      }
    }
  }
}

// ---------------- fused pass1: rowsums + col partials + attn_img stats --------
__global__ __launch_bounds__(256) void gstats_kernel(
    const ushort* __restrict__ G, float* __restrict__ rs_t,
    float* __restrict__ csp, float* __restrict__ pm, float* __restrict__ ps) {
  __shared__ float redm[4][LT];
  __shared__ float reds[4][LT];
  int blk = blockIdx.x;
  int b = blk >> 2, ch = blk & 3;
  int w = threadIdx.x >> 6, lane = threadIdx.x & 63;
  const ushort* g = G + (size_t)b * LI * LT;
  int i0 = ch * 144;
  float c0 = 0.f, c1 = 0.f, c2 = 0.f, c3 = 0.f;
  float m0 = -1e30f, m1 = -1e30f, m2 = -1e30f, m3 = -1e30f;
  float s0 = 0.f, s1 = 0.f, s2 = 0.f, s3 = 0.f;
  for (int k = 0; k < 36; ++k) {
    int i = i0 + k * 4 + w;
    ushort4 u = reinterpret_cast<const ushort4*>(g + (size_t)i * LT)[lane];
    float r0 = fmaxf(b2f(u.x), 0.f), r1 = fmaxf(b2f(u.y), 0.f);
    float r2 = fmaxf(b2f(u.z), 0.f), r3 = fmaxf(b2f(u.w), 0.f);
    c0 += r0; c1 += r1; c2 += r2; c3 += r3;
    float s = r0 + r1 + r2 + r3;
    #pragma unroll
    for (int off = 32; off > 0; off >>= 1) s += __shfl_xor(s, off);
    if (lane == 0) rs_t[b * LI + i] = s;
    float inv = SMOOTHF / (s + EPSF);
    float x0 = r0 * inv, x1 = r1 * inv, x2 = r2 * inv, x3 = r3 * inv;
    float mn;
    mn = fmaxf(m0, x0); s0 = s0 * __expf(m0 - mn) + __expf(x0 - mn); m0 = mn;
    mn = fmaxf(m1, x1); s1 = s1 * __expf(m1 - mn) + __expf(x1 - mn); m1 = mn;
    mn = fmaxf(m2, x2); s2 = s2 * __expf(m2 - mn) + __expf(x2 - mn); m2 = mn;
    mn = fmaxf(m3, x3); s3 = s3 * __expf(m3 - mn) + __expf(x3 - mn); m3 = mn;
  }
  int t = threadIdx.x;
  redm[w][lane * 4 + 0] = c0; redm[w][lane * 4 + 1] = c1;
  redm[w][lane * 4 + 2] = c2; redm[w][lane * 4 + 3] = c3;
  __syncthreads();
  csp[(size_t)blk * LT + t] = redm[0][t] + redm[1][t] + redm[2][t] + redm[3][t];
  __syncthreads();
  redm[w][lane * 4 + 0] = m0; redm[w][lane * 4 + 1] = m1;
  redm[w][lane * 4 + 2] = m2; redm[w][lane * 4 + 3] = m3;
  reds[w][lane * 4 + 0] = s0; reds[w][lane * 4 + 1] = s1;
  reds[w][lane * 4 + 2] = s2; reds[w][lane * 4 + 3] = s3;
  __syncthreads();
  float mm = fmaxf(fmaxf(redm[0][t], redm[1][t]), fmaxf(redm[2][t], redm[3][t]));
  float ss = reds[0][t] * __expf(redm[0][t] - mm) + reds[1][t] * __expf(redm[1][t] - mm)
           + reds[2][t] * __expf(redm[2][t] - mm) + reds[3][t] * __expf(redm[3][t] - mm);
  pm[(size_t)blk * LT + t] = mm;
  ps[(size_t)blk * LT + t] = ss;
}

// ---------------- combine: rs_i + final attn_img stats ----------------
__global__ __launch_bounds__(256) void combine_kernel(
    const float* __restrict__ csp, const float* __restrict__ pm,
    const float* __restrict__ ps, float* __restrict__ rs_i,
    float* __restrict__ m_out, float* __restrict__ s_out) {
  int b = blockIdx.x, t = threadIdx.x;
  float cs = 0.f;
  #pragma unroll
  for (int q = 0; q < 4; ++q) cs += csp[(size_t)(b * 4 + q) * LT + t];
  rs_i[b * LT + t] = cs;
  float m = -1e30f;
  #pragma unroll
  for (int q = 0; q < 4; ++q) m = fmaxf(m, pm[(size_t)(b * 4 + q) * LT + t]);
  float s = 0.f;
  #pragma unroll
  for (int q = 0; q < 4; ++q)
    s += ps[(size_t)(b * 4 + q) * LT + t] * __expf(pm[(size_t)(b * 4 + q) * LT + t] - m);
  m_out[b * LT + t] = m;
  s_out[b * LT + t] = s;
}

// ---------------- fused pass2: attn_txt + attn_img from one G tile ----------
__global__ __launch_bounds__(256) void attn_fused_kernel(
    const ushort* __restrict__ G, const float* __restrict__ rs_i,
    const float* __restrict__ rs_t, const float* __restrict__ mi,
    const float* __restrict__ si,
    float* __restrict__ at_f32, ushort* __restrict__ at_b16,
    float* __restrict__ ai_f32, ushort* __restrict__ ai_b16) {
  __shared__ ushort Gs[64][264];     // bf16 tile, +8 pad
  __shared__ float  T[64][65];
  __shared__ float  invl_s[64];
  int b = blockIdx.y, i0 = blockIdx.x * 64;
  int q = threadIdx.x;
  { // load tile: rows coalesced
    int row = q >> 2, c0 = (q & 3) * 64;
    const ushort* src = G + ((size_t)b * LI + i0 + row) * LT + c0;
    #pragma unroll
    for (int e = 0; e < 8; ++e) {
      uint4 v = *reinterpret_cast<const uint4*>(src + e * 8);
      *reinterpret_cast<uint4*>(&Gs[row][c0 + e * 8]) = v;
    }
  }
  if (q < 64) invl_s[q] = SMOOTHF / (rs_t[b * LI + i0 + q] + EPSF);
  __syncthreads();

  // ---- phase A: attn_txt (row softmax over t) ----
  {
    int w = q >> 6, lane = q & 63;
    float4 dv = reinterpret_cast<const float4*>(rs_i + (size_t)b * LT)[lane];
    float i0d = SMOOTHF / (dv.x + EPSF), i1d = SMOOTHF / (dv.y + EPSF);
    float i2d = SMOOTHF / (dv.z + EPSF), i3d = SMOOTHF / (dv.w + EPSF);
    #pragma unroll 4
    for (int rr = 0; rr < 16; ++rr) {
      int row = w * 16 + rr;
      ushort4 gu = *reinterpret_cast<const ushort4*>(&Gs[row][lane * 4]);
      float x0 = fmaxf(b2f(gu.x), 0.f) * i0d;
      float x1 = fmaxf(b2f(gu.y), 0.f) * i1d;
      float x2 = fmaxf(b2f(gu.z), 0.f) * i2d;
      float x3 = fmaxf(b2f(gu.w), 0.f) * i3d;
      float m = fmaxf(fmaxf(x0, x1), fmaxf(x2, x3));
      #pragma unroll
      for (int off = 32; off > 0; off >>= 1) m = fmaxf(m, __shfl_xor(m, off));
      float e0 = __expf(x0 - m), e1 = __expf(x1 - m);
      float e2 = __expf(x2 - m), e3 = __expf(x3 - m);
      float s = e0 + e1 + e2 + e3;
      #pragma unroll
      for (int off = 32; off > 0; off >>= 1) s += __shfl_xor(s, off);
      float inv = 1.0f / s;
      float4 o = make_float4(e0 * inv, e1 * inv, e2 * inv, e3 * inv);
      size_t roff = ((size_t)b * LI + i0 + row) * LT;
      reinterpret_cast<float4*>(at_f32 + roff)[lane] = o;
      reinterpret_cast<ushort4*>(at_b16 + roff)[lane] =
          make_ushort4(f2b(o.x), f2b(o.y), f2b(o.z), f2b(o.w));
    }
  }

  // ---- phase B: attn_img, 4 x (64t x 64i) transposed subtiles ----
  for (int tt = 0; tt < 4; ++tt) {
    __syncthreads();
    {
      int row = q >> 2;
      int t4  = (q & 3) * 16;
      float invl = invl_s[row];
      const float* mip = mi + (size_t)b * LT + tt * 64 + t4;
      const float* sip = si + (size_t)b * LT + tt * 64 + t4;
      float mt[16], ist[16];
      #pragma unroll
      for (int e4 = 0; e4 < 4; ++e4) {
        float4 mv = *reinterpret_cast<const float4*>(mip + e4 * 4);
        float4 sv = *reinterpret_cast<const float4*>(sip + e4 * 4);
        mt[e4 * 4 + 0] = mv.x; mt[e4 * 4 + 1] = mv.y;
        mt[e4 * 4 + 2] = mv.z; mt[e4 * 4 + 3] = mv.w;
        ist[e4 * 4 + 0] = 1.0f / sv.x; ist[e4 * 4 + 1] = 1.0f / sv.y;
        ist[e4 * 4 + 2] = 1.0f / sv.z; ist[e4 * 4 + 3] = 1.0f / sv.w;
      }
      #pragma unroll
      for (int u = 0; u < 2; ++u) {
        ushort gu[8];
        *reinterpret_cast<uint4*>(gu) =
            *reinterpret_cast<const uint4*>(&Gs[row][tt * 64 + t4 + u * 8]);
        #pragma unroll
        for (int e = 0; e < 8; ++e) {
          int idx = u * 8 + e;
          float x = fmaxf(b2f(gu[e]), 0.f) * invl;
          T[t4 + idx][row] = __expf(x - mt[idx]) * ist[idx];
        }
      }
    }
    __syncthreads();
    {
      int trow = q >> 2;
      int i4   = (q & 3) * 16;
      size_t off = ((size_t)b * LT + tt * 64 + trow) * LI + i0 + i4;
      #pragma unroll
      for (int e4 = 0; e4 < 4; ++e4) {
        float4 o = make_float4(T[trow][i4 + e4 * 4], T[trow][i4 + e4 * 4 + 1],
                               T[trow][i4 + e4 * 4 + 2], T[trow][i4 + e4 * 4 + 3]);
        *reinterpret_cast<float4*>(ai_f32 + off + e4 * 4) = o;
        reinterpret_cast<ushort4*>(ai_b16 + off)[e4] =
            make_ushort4(f2b(o.x), f2b(o.y), f2b(o.z), f2b(o.w));
      }
    }
  }
}

// ---------------- launch ----------------
extern "C" void kernel_launch(void* const* d_in, const int* in_sizes, int n_in,
                              void* d_out, int out_size, void* d_ws, size_t ws_size,
                              hipStream_t stream) {
  const float* txt   = (const float*)d_in[0];
  const float* img   = (const float*)d_in[1];
  const float* W_txt = (const float*)d_in[2];
  const float* b_txt = (const float*)d_in[3];
  const float* W_img = (const float*)d_in[4];
  const float* b_img = (const float*)d_in[5];

  float* out          = (float*)d_out;
  float* out_txt      = out;
  float* out_img      = out + (size_t)B_ * LT * HD;
  float* out_attn_img = out_img + (size_t)B_ * LI * HD;
  float* out_attn_txt = out_attn_img + (size_t)B_ * LT * LI;

  char* w = (char*)d_ws;
  auto alloc = [&](size_t bytes) -> char* {
    char* p = w; w += (bytes + 255) & ~(size_t)255; return p;
  };
  ushort* txt_b  = (ushort*)alloc((size_t)B_ * LT * HD * 2);
  ushort* img_b  = (ushort*)alloc((size_t)B_ * LI * HD * 2);
  ushort* Wt_b   = (ushort*)alloc((size_t)HD * HD * 2);
  ushort* Wi_b   = (ushort*)alloc((size_t)HD * HD * 2);
  ushort* Gm_b   = (ushort*)alloc((size_t)B_ * LI * LT * 2);
  float*  rs_t   = (float*) alloc((size_t)B_ * LI * 4);
  float*  csp    = (float*) alloc((size_t)B_ * 4 * LT * 4);
  float*  pm     = (float*) alloc((size_t)B_ * 4 * LT * 4);
  float*  ps     = (float*) alloc((size_t)B_ * 4 * LT * 4);
  float*  rs_i   = (float*) alloc((size_t)B_ * LT * 4);
  float*  mi     = (float*) alloc((size_t)B_ * LT * 4);
  float*  si     = (float*) alloc((size_t)B_ * LT * 4);
  ushort* ai_b   = (ushort*)alloc((size_t)B_ * LT * LI * 2);
  ushort* at_b   = (ushort*)alloc((size_t)B_ * LI * LT * 2);
  ushort* txtAE  = (ushort*)alloc((size_t)B_ * LT * HD * 2);
  ushort* Pf     = (ushort*)alloc((size_t)B_ * LT * HD * 2);   // txtF . W_img^T  [b,t,o]
  (void)ws_size; (void)in_sizes; (void)n_in; (void)out_size;   // ~453 MB

  // bf16 conversions
  cvt_bf16_kernel<<<2048, 256, 0, stream>>>(txt, txt_b, B_ * LT * HD / 4);
  cvt_bf16_kernel<<<2048, 256, 0, stream>>>(img, img_b, B_ * LI * HD / 4);
  cvt_bf16_kernel<<<1024, 256, 0, stream>>>(W_txt, Wt_b, HD * HD / 4);
  cvt_bf16_kernel<<<1024, 256, 0, stream>>>(W_img, Wi_b, HD * HD / 4);

  // G[b,i,t] = img[b,i,:].txt[b,t,:]  -> bf16 (NT, M=576 pred)
  dim3 gG(5 * (LT / 128), B_);
  gemm128<false, true, true, false, false><<<gG, 256, 0, stream>>>(
      img_b, txt_b, nullptr, Gm_b, LI, LT, HD,
      (long)LI * HD, (long)LT * HD, (long)LI * LT, HD, HD, LT);

  // pass1: rowsums + col partials + attn_img online stats (one G read)
  gstats_kernel<<<B_ * 4, 256, 0, stream>>>(Gm_b, rs_t, csp, pm, ps);
  combine_kernel<<<B_, 256, 0, stream>>>(csp, pm, ps, rs_i, mi, si);

  // pass2: attn_txt + attn_img outputs (one G read)
  attn_fused_kernel<<<dim3(LI / 64, B_), 256, 0, stream>>>(
      Gm_b, rs_i, rs_t, mi, si, out_attn_txt, at_b, out_attn_img, ai_b);

  // Pf = txtF . W_img^T  (flattened NT, 256^2 counted-vmcnt kernel) -> [b,t,o]
  gemm256<true, false><<<(B_ * LT / 256) * (HD / 256), 512, 131072, stream>>>(
      txt_b, Wi_b, nullptr, Pf, HD, HD, HD, HD, HD);

  // txtAE = attn_img . img   (BT: B=img [K=LI][N=HD], transpose-staged)
  dim3 g1((LT / 128) * (HD / 128), B_);
  gemm128<true, false, true, false, false><<<g1, 256, 0, stream>>>(
      ai_b, img_b, nullptr, txtAE, LT, HD, LI,
      (long)LT * LI, (long)LI * HD, (long)LT * HD, LI, HD, HD);

  // FC txt head flattened: relu(txtAE @ Wt^T + b)  (256^2 counted-vmcnt kernel)
  gemm256<false, true><<<(B_ * LT / 256) * (HD / 256), 512, 131072, stream>>>(
      txtAE, Wt_b, b_txt, out_txt, HD, HD, HD, HD, HD);

  // out_img = relu(attn_txt . Pf[b]^T + b_img)   (BT: B=Pf[b] [K=LT][N=HD])
  dim3 g2(5 * (HD / 128), B_);
  gemm128<true, true, false, true, false><<<g2, 256, 0, stream>>>(
      at_b, Pf, b_img, out_img, LI, HD, LT,
      (long)LI * LT, (long)LT * HD, (long)LI * HD, LT, HD, HD);
}